// Round 2
// baseline (1348.608 us; speedup 1.0000x reference)
//
#include <hip/hip_runtime.h>
#include <hip/hip_bf16.h>
#include <stdint.h>

typedef unsigned short u16;
typedef unsigned int u32;

#define T_TOK 8192
#define H_DIM 1024
#define I_DIM 2816
#define NE 8

typedef __bf16 bf16x8 __attribute__((ext_vector_type(8)));
typedef float f32x4 __attribute__((ext_vector_type(4)));

union F8 { uint4 v; bf16x8 f; u32 w[4]; };

__device__ __forceinline__ u16 f2bf(float f) {
    u32 u = __float_as_uint(f);
    u32 r = u + 0x7FFFu + ((u >> 16) & 1u);
    return (u16)(r >> 16);
}
// pack two f32 -> one dword of two bf16 (lo = a, hi = b); RNE
__device__ __forceinline__ u32 pkbf(float a, float b) {
    float2 f; f.x = a; f.y = b;
    __hip_bfloat162 h = __float22bfloat162_rn(f);
    union { __hip_bfloat162 h2; u32 w; } cv; cv.h2 = h;
    return cv.w;
}

// async global->LDS, 16B per lane. LDS dest must be wave-uniform base (lane*16 implicit).
__device__ __forceinline__ void g2l16(const void* g, void* l) {
    __builtin_amdgcn_global_load_lds(
        (const __attribute__((address_space(1))) u32*)g,
        (__attribute__((address_space(3))) u32*)l, 16, 0, 0);
}

// ---------------- zero cnt ----------------
__global__ void zero_cnt_kernel(int* __restrict__ cnt) {
    if (threadIdx.x < NE) cnt[threadIdx.x] = 0;
}

// ---------------- zero out0 (legacy atomic path only) ----------------
__global__ void __launch_bounds__(256) zero_out_kernel(float* __restrict__ out0) {
    int gid = blockIdx.x * 256 + threadIdx.x;
    f32x4 z = {0.f, 0.f, 0.f, 0.f};
    ((f32x4*)out0)[gid] = z;
}

// ---------------- x f32 -> bf16 ----------------
__global__ void __launch_bounds__(256) xcvt_kernel(const float* __restrict__ x, u16* __restrict__ xb) {
    size_t gid = (size_t)blockIdx.x * 256 + threadIdx.x;
    const float4* s = (const float4*)x + gid * 2;
    float4 a = s[0], b = s[1];
    uint4 o;
    o.x = pkbf(a.x, a.y); o.y = pkbf(a.z, a.w);
    o.z = pkbf(b.x, b.y); o.w = pkbf(b.z, b.w);
    ((uint4*)xb)[gid] = o;
}

// ---------------- weight pack: src [e][K][N] f32 -> dst [e][N][K/2] u32 (bf16 k-pairs) ----------------
__global__ void __launch_bounds__(256)
pack_kernel(const float* __restrict__ src, u32* __restrict__ dst, int K, int N) {
    int e = blockIdx.z;
    int n0 = blockIdx.x * 64;
    int r0 = blockIdx.y * 128;          // k-row base (128 rows = 64 k2)
    __shared__ float sT[128][65];
    int tid = threadIdx.x;
    const float* sp = src + ((size_t)e * K + r0) * N + n0;
#pragma unroll
    for (int rep = 0; rep < 8; rep++) {
        int row = rep * 16 + (tid >> 4);
        int n4 = (tid & 15) * 4;
        float4 v = *(const float4*)(sp + (size_t)row * N + n4);
        sT[row][n4] = v.x; sT[row][n4 + 1] = v.y; sT[row][n4 + 2] = v.z; sT[row][n4 + 3] = v.w;
    }
    __syncthreads();
    int n = tid >> 2, q = tid & 3;
    u32* dp = dst + ((size_t)e * N + n0 + n) * (size_t)(K >> 1) + (r0 >> 1) + q * 16;
    uint4 o[4];
    u32* ow = (u32*)o;
#pragma unroll
    for (int j = 0; j < 16; j++) {
        int k2 = q * 16 + j;
        ow[j] = pkbf(sT[2 * k2][n], sT[2 * k2 + 1][n]);
    }
#pragma unroll
    for (int j = 0; j < 4; j++) ((uint4*)dp)[j] = o[j];
}

// ---------------- router (f32): logits + softmax top-2 + expert lists ----------------
__global__ void __launch_bounds__(256)
router_kernel(const float* __restrict__ x, const float* __restrict__ gw,
              float* __restrict__ logits_out, float* __restrict__ wbuf,
              int* __restrict__ cnt, int* __restrict__ idxlist) {
    int lane = threadIdx.x & 63;
    int t = blockIdx.x * 4 + (threadIdx.x >> 6);
    const float* xr = x + (size_t)t * H_DIM;
    float acc[NE];
#pragma unroll
    for (int e = 0; e < NE; e++) acc[e] = 0.f;
#pragma unroll
    for (int i = 0; i < 16; i++) {
        int hh = i * 64 + lane;
        float xv = xr[hh];
        const float4* grow = (const float4*)(gw + (size_t)hh * NE);
        float4 g0 = grow[0], g1 = grow[1];
        acc[0] += xv * g0.x; acc[1] += xv * g0.y;
        acc[2] += xv * g0.z; acc[3] += xv * g0.w;
        acc[4] += xv * g1.x; acc[5] += xv * g1.y;
        acc[6] += xv * g1.z; acc[7] += xv * g1.w;
    }
#pragma unroll
    for (int m = 32; m >= 1; m >>= 1) {
#pragma unroll
        for (int e = 0; e < NE; e++) acc[e] += __shfl_xor(acc[e], m, 64);
    }
    if (lane == 0) {
        float mx = acc[0];
#pragma unroll
        for (int e = 1; e < NE; e++) mx = fmaxf(mx, acc[e]);
        float p[NE];
#pragma unroll
        for (int e = 0; e < NE; e++) p[e] = __expf(acc[e] - mx);
        float4 l0, l1;
        l0.x = acc[0]; l0.y = acc[1]; l0.z = acc[2]; l0.w = acc[3];
        l1.x = acc[4]; l1.y = acc[5]; l1.z = acc[6]; l1.w = acc[7];
        float4* lrow_p = (float4*)(logits_out + (size_t)t * NE);
        lrow_p[0] = l0; lrow_p[1] = l1;
        int a = 0; float pa = p[0];
#pragma unroll
        for (int e = 1; e < NE; e++) if (p[e] > pa) { a = e; pa = p[e]; }
        int b = -1; float pb = -1.f;
#pragma unroll
        for (int e = 0; e < NE; e++) if (e != a && p[e] > pb) { b = e; pb = p[e]; }
        if (b < 0) { b = a ^ 1; pb = p[b]; }
        float inv = 1.f / (pa + pb);
        wbuf[2 * t]     = pa * inv;
        wbuf[2 * t + 1] = pb * inv;
        int pos = atomicAdd(&cnt[a], 1); idxlist[a * T_TOK + pos] = 2 * t;
        pos = atomicAdd(&cnt[b], 1);     idxlist[b * T_TOK + pos] = 2 * t + 1;
    }
}

// ---------------- grouped gate+up GEMM (I-chunk), all-bf16 pre-packed inputs ----------------
// Tile 128x128, BK=32, 4 waves, DOUBLE-BUFFERED LDS with prefetch-after-barrier:
//   stage(t=0); loop { __syncthreads(); stage(t+1 -> other buf); compute(cur); }
// One barrier per K-step; the barrier's vmcnt(0) drain waits on loads that flew
// during the previous compute phase (T3 minimum 2-phase).
__global__ void __launch_bounds__(256, 3)
gateup_kernel(const u16* __restrict__ xb, const u32* __restrict__ wgp,
              const u32* __restrict__ wup, const int* __restrict__ cnt,
              const int* __restrict__ idxlist, u16* __restrict__ hchunk,
              int nbase, int nlen) {
    // XCD-grouped mapping: consecutive blocks on one XCD share the (e,n) B-strip.
    int NN = nlen >> 7;
    int pid = blockIdx.x;
    int xcd = pid & 7;
    int j = pid >> 3;
    int m = j & 63;
    int gs = j >> 6;
    int g = xcd + (gs << 3);
    int e = g / NN;
    int nb = g - e * NN;
    int c = cnt[e];
    int m0 = m * 128;
    if (m0 >= c) return;
    int n0l = nb * 128;
    int n0g = nbase + n0l;

    __shared__ alignas(16) u16 sA[2][128 * 32];   // 8 KB each
    __shared__ alignas(16) u32 sBg[2][128 * 16];  // 8 KB each
    __shared__ alignas(16) u32 sBu[2][128 * 16];  // 8 KB each
    int tid = threadIdx.x;
    int wv = tid >> 6;

    // staging geometry: 4 chunks of 16B per row; phys chunk p holds source chunk p^(row&3)
    int row_lo = tid >> 2;               // 0..63
    int csw = tid & 3;
    const u16* aP[2];
#pragma unroll
    for (int p = 0; p < 2; p++) {
        int row = p * 64 + row_lo;
        int jj = m0 + row; if (jj > c - 1) jj = c - 1;
        int slot = idxlist[e * T_TOK + jj];
        aP[p] = xb + (size_t)(slot >> 1) * H_DIM + ((csw ^ (row_lo & 3)) << 3);
    }
    size_t bn = (size_t)e * I_DIM + n0g + row_lo;
    int bsw = (csw ^ (row_lo & 3)) << 2;  // u32 offset of source chunk
    const u32* bgB = wgp + bn * 512 + bsw;
    const u32* buB = wup + bn * 512 + bsw;

    auto stage = [&](int k0, int buf) {
#pragma unroll
        for (int p = 0; p < 2; p++)
            g2l16(aP[p] + k0, &sA[buf][(p * 256 + wv * 64) * 8]);
#pragma unroll
        for (int p = 0; p < 2; p++)
            g2l16(bgB + (size_t)p * 64 * 512 + (k0 >> 1), &sBg[buf][(p * 256 + wv * 64) * 4]);
#pragma unroll
        for (int p = 0; p < 2; p++)
            g2l16(buB + (size_t)p * 64 * 512 + (k0 >> 1), &sBu[buf][(p * 256 + wv * 64) * 4]);
    };

    int lane = tid & 63;
    int wm = (tid >> 7) & 1, wn = (tid >> 6) & 1;
    int lrow = lane & 15, quad = lane >> 4;
    f32x4 zero = {0.f, 0.f, 0.f, 0.f};
    f32x4 accg[4][4], accu[4][4];
#pragma unroll
    for (int mi = 0; mi < 4; mi++)
#pragma unroll
        for (int ni = 0; ni < 4; ni++) { accg[mi][ni] = zero; accu[mi][ni] = zero; }

    stage(0, 0);
#pragma unroll 2
    for (int k0 = 0; k0 < H_DIM; k0 += 32) {
        int buf = (k0 >> 5) & 1;
        __syncthreads();                  // drains this wave's prefetch, frees other buf
        if (k0 + 32 < H_DIM) stage(k0 + 32, buf ^ 1);
        bf16x8 af[4]; F8 bg[4], bu[4];
#pragma unroll
        for (int i = 0; i < 4; i++) {
            int ra = wm * 64 + i * 16 + lrow;
            af[i] = *(const bf16x8*)&sA[buf][((ra << 2) + (quad ^ (ra & 3))) * 8];
            int n = wn * 64 + i * 16 + lrow;
            bg[i].v = *(const uint4*)&sBg[buf][((n << 2) + (quad ^ (n & 3))) * 4];
            bu[i].v = *(const uint4*)&sBu[buf][((n << 2) + (quad ^ (n & 3))) * 4];
        }
#pragma unroll
        for (int mi = 0; mi < 4; mi++)
#pragma unroll
            for (int ni = 0; ni < 4; ni++) {
                accg[mi][ni] = __builtin_amdgcn_mfma_f32_16x16x32_bf16(af[mi], bg[ni].f, accg[mi][ni], 0, 0, 0);
                accu[mi][ni] = __builtin_amdgcn_mfma_f32_16x16x32_bf16(af[mi], bu[ni].f, accu[mi][ni], 0, 0, 0);
            }
    }
    // epilogue: h = silu(g)*u; C/D layout col=lane&15, row=quad*4+reg
#pragma unroll
    for (int mi = 0; mi < 4; mi++) {
#pragma unroll
        for (int r = 0; r < 4; r++) {
            int grow = m0 + wm * 64 + mi * 16 + quad * 4 + r;
            if (grow < c) {
                int slot = idxlist[e * T_TOK + grow];
                u16* hrow = hchunk + (size_t)slot * nlen + n0l + wn * 64 + lrow;
#pragma unroll
                for (int ni = 0; ni < 4; ni++) {
                    float gv = accg[mi][ni][r], uv = accu[mi][ni][r];
                    float hv = gv * uv / (1.f + __expf(-gv));
                    hrow[ni * 16] = f2bf(hv);
                }
            }
        }
    }
}

// ---------------- grouped down GEMM chunk (BK=32, double-buffered) ----------------
__global__ void __launch_bounds__(256, 3)
down_kernel(const u16* __restrict__ hchunk, const u32* __restrict__ wdp,
            const int* __restrict__ cnt, const int* __restrict__ idxlist,
            const float* __restrict__ wbuf, float* __restrict__ out0,
            float* __restrict__ ybuf, int kbase, int klen, int beta) {
    int pid = blockIdx.x;
    int xcd = pid & 7;
    int j = pid >> 3;
    int m = j & 63;
    int gs = j >> 6;
    int g = xcd + (gs << 3);   // 0..63 = e*8 + nb
    int e = g >> 3;
    int nb = g & 7;
    int c = cnt[e];
    int m0 = m * 128;
    if (m0 >= c) return;
    int n0 = nb * 128;

    __shared__ alignas(16) u16 sA[2][128 * 32];
    __shared__ alignas(16) u32 sB[2][128 * 16];
    int tid = threadIdx.x;
    int wv = tid >> 6;

    int row_lo = tid >> 2;
    int csw = tid & 3;
    const u16* aP[2];
#pragma unroll
    for (int p = 0; p < 2; p++) {
        int row = p * 64 + row_lo;
        int jj = m0 + row; if (jj > c - 1) jj = c - 1;
        int slot = idxlist[e * T_TOK + jj];
        aP[p] = hchunk + (size_t)slot * klen + ((csw ^ (row_lo & 3)) << 3);
    }
    int bsw = (csw ^ (row_lo & 3)) << 2;
    const u32* bB = wdp + ((size_t)e * H_DIM + n0 + row_lo) * 1408 + (kbase >> 1) + bsw;

    auto stage = [&](int k0, int buf) {
#pragma unroll
        for (int p = 0; p < 2; p++)
            g2l16(aP[p] + k0, &sA[buf][(p * 256 + wv * 64) * 8]);
#pragma unroll
        for (int p = 0; p < 2; p++)
            g2l16(bB + (size_t)p * 64 * 1408 + (k0 >> 1), &sB[buf][(p * 256 + wv * 64) * 4]);
    };

    int lane = tid & 63;
    int wm = (tid >> 7) & 1, wn = (tid >> 6) & 1;
    int lrow = lane & 15, quad = lane >> 4;
    f32x4 zero = {0.f, 0.f, 0.f, 0.f};
    f32x4 acc[4][4];
#pragma unroll
    for (int mi = 0; mi < 4; mi++)
#pragma unroll
        for (int ni = 0; ni < 4; ni++) acc[mi][ni] = zero;

    stage(0, 0);
#pragma unroll 2
    for (int k0 = 0; k0 < klen; k0 += 32) {
        int buf = (k0 >> 5) & 1;
        __syncthreads();
        if (k0 + 32 < klen) stage(k0 + 32, buf ^ 1);
        bf16x8 af[4]; F8 bf[4];
#pragma unroll
        for (int i = 0; i < 4; i++) {
            int ra = wm * 64 + i * 16 + lrow;
            af[i] = *(const bf16x8*)&sA[buf][((ra << 2) + (quad ^ (ra & 3))) * 8];
            int n = wn * 64 + i * 16 + lrow;
            bf[i].v = *(const uint4*)&sB[buf][((n << 2) + (quad ^ (n & 3))) * 4];
        }
#pragma unroll
        for (int mi = 0; mi < 4; mi++)
#pragma unroll
            for (int ni = 0; ni < 4; ni++)
                acc[mi][ni] = __builtin_amdgcn_mfma_f32_16x16x32_bf16(af[mi], bf[ni].f, acc[mi][ni], 0, 0, 0);
    }
#pragma unroll
    for (int mi = 0; mi < 4; mi++) {
#pragma unroll
        for (int r = 0; r < 4; r++) {
            int grow = m0 + wm * 64 + mi * 16 + quad * 4 + r;
            if (grow < c) {
                int slot = idxlist[e * T_TOK + grow];
                if (ybuf) {
                    float* yrow = ybuf + (size_t)slot * H_DIM + n0 + wn * 64 + lrow;
                    if (beta) {
#pragma unroll
                        for (int ni = 0; ni < 4; ni++) yrow[ni * 16] += acc[mi][ni][r];
                    } else {
#pragma unroll
                        for (int ni = 0; ni < 4; ni++) yrow[ni * 16] = acc[mi][ni][r];
                    }
                } else {
                    float w = wbuf[slot];
                    float* yrow = out0 + (size_t)(slot >> 1) * H_DIM + n0 + wn * 64 + lrow;
#pragma unroll
                    for (int ni = 0; ni < 4; ni++)
                        atomicAdd(&yrow[ni * 16], w * acc[mi][ni][r]);
                }
            }
        }
    }
}

// ---------------- combine: out[t] = w0*y[2t] + w1*y[2t+1] ----------------
__global__ void __launch_bounds__(256)
combine_kernel(const float* __restrict__ ybuf, const float* __restrict__ wbuf,
               float* __restrict__ out0) {
    int gid = blockIdx.x * 256 + threadIdx.x;
    int t = gid >> 8;            // H_DIM/4 = 256 f32x4 per row
    int h4 = gid & 255;
    float w0 = wbuf[2 * t], w1 = wbuf[2 * t + 1];
    f32x4 a = ((const f32x4*)(ybuf + (size_t)(2 * t) * H_DIM))[h4];
    f32x4 b = ((const f32x4*)(ybuf + (size_t)(2 * t + 1) * H_DIM))[h4];
    f32x4 o;
#pragma unroll
    for (int i = 0; i < 4; i++) o[i] = w0 * a[i] + w1 * b[i];
    ((f32x4*)(out0 + (size_t)t * H_DIM))[h4] = o;
}

extern "C" void kernel_launch(void* const* d_in, const int* in_sizes, int n_in,
                              void* d_out, int out_size, void* d_ws, size_t ws_size,
                              hipStream_t stream) {
    (void)in_sizes; (void)n_in; (void)out_size;
    const float* x  = (const float*)d_in[0];
    const float* gw = (const float*)d_in[1];
    const float* wg = (const float*)d_in[2];
    const float* wu = (const float*)d_in[3];
    const float* wd = (const float*)d_in[4];
    float* out = (float*)d_out;
    float* logits = out + (size_t)T_TOK * H_DIM;
    char* ws = (char*)d_ws;

    size_t off = 0;
    auto take = [&](size_t sz) { char* p = ws + off; off += (sz + 255) & ~(size_t)255; return p; };
    int* cnt      = (int*)take(NE * 4);
    int* idxlist  = (int*)take((size_t)NE * T_TOK * 4);
    float* wbuf   = (float*)take((size_t)2 * T_TOK * 4);
    u16* xb       = (u16*)take((size_t)T_TOK * H_DIM * 2);            // 16.8 MB
    u32* wgp      = (u32*)take((size_t)NE * I_DIM * 512 * 4);         // 46.1 MB
    u32* wup      = (u32*)take((size_t)NE * I_DIM * 512 * 4);         // 46.1 MB
    u32* wdp      = (u32*)take((size_t)NE * H_DIM * 1408 * 4);        // 46.1 MB
    float* ybuf = nullptr;
    size_t ybytes = (size_t)2 * T_TOK * H_DIM * 4;                    // 67.1 MB
    size_t minh   = (size_t)2 * T_TOK * 128 * 2 + 256;
    if (ws_size >= off + ybytes + minh) ybuf = (float*)take(ybytes);
    int ich = I_DIM;
    while (ich > 128 && off + (size_t)2 * T_TOK * ich * 2 > ws_size) ich -= 128;
    u16* hchunk = (u16*)(ws + off);

    zero_cnt_kernel<<<1, 64, 0, stream>>>(cnt);
    if (!ybuf) zero_out_kernel<<<T_TOK * H_DIM / 4 / 256, 256, 0, stream>>>(out);
    pack_kernel<<<dim3(I_DIM / 64, H_DIM / 128, NE), 256, 0, stream>>>(wg, wgp, H_DIM, I_DIM);
    pack_kernel<<<dim3(I_DIM / 64, H_DIM / 128, NE), 256, 0, stream>>>(wu, wup, H_DIM, I_DIM);
    pack_kernel<<<dim3(H_DIM / 64, I_DIM / 128, NE), 256, 0, stream>>>(wd, wdp, I_DIM, H_DIM);
    xcvt_kernel<<<T_TOK * H_DIM / 8 / 256, 256, 0, stream>>>(x, xb);
    router_kernel<<<T_TOK / 4, 256, 0, stream>>>(x, gw, logits, wbuf, cnt, idxlist);
    for (int base = 0; base < I_DIM; base += ich) {
        int len = I_DIM - base; if (len > ich) len = ich;
        int NN = len / 128;
        gateup_kernel<<<64 * NN * NE, 256, 0, stream>>>(xb, wgp, wup, cnt, idxlist, hchunk, base, len);
        down_kernel<<<64 * 8 * NE, 256, 0, stream>>>(hchunk, wdp, cnt, idxlist, wbuf, out, ybuf, base, len, base > 0 ? 1 : 0);
    }
    if (ybuf) combine_kernel<<<T_TOK * H_DIM / 4 / 256, 256, 0, stream>>>(ybuf, wbuf, out);
}

// Round 3
// 1011.024 us; speedup vs baseline: 1.3339x; 1.3339x over previous
//
#include <hip/hip_runtime.h>
#include <hip/hip_bf16.h>
#include <stdint.h>

typedef unsigned short u16;
typedef unsigned int u32;

#define T_TOK 8192
#define H_DIM 1024
#define I_DIM 2816
#define NE 8

typedef __bf16 bf16x8 __attribute__((ext_vector_type(8)));
typedef float f32x4 __attribute__((ext_vector_type(4)));

union F8 { uint4 v; bf16x8 f; u32 w[4]; };

__device__ __forceinline__ u16 f2bf(float f) {
    u32 u = __float_as_uint(f);
    u32 r = u + 0x7FFFu + ((u >> 16) & 1u);
    return (u16)(r >> 16);
}
// pack two f32 -> one dword of two bf16 (lo = a, hi = b); RNE
__device__ __forceinline__ u32 pkbf(float a, float b) {
    float2 f; f.x = a; f.y = b;
    __hip_bfloat162 h = __float22bfloat162_rn(f);
    union { __hip_bfloat162 h2; u32 w; } cv; cv.h2 = h;
    return cv.w;
}

// async global->LDS, 16B per lane. LDS dest must be wave-uniform base (lane*16 implicit).
__device__ __forceinline__ void g2l16(const void* g, void* l) {
    __builtin_amdgcn_global_load_lds(
        (const __attribute__((address_space(1))) u32*)g,
        (__attribute__((address_space(3))) u32*)l, 16, 0, 0);
}

// ---------------- zero cnt ----------------
__global__ void zero_cnt_kernel(int* __restrict__ cnt) {
    if (threadIdx.x < NE) cnt[threadIdx.x] = 0;
}

// ---------------- zero out0 (legacy atomic path only) ----------------
__global__ void __launch_bounds__(256) zero_out_kernel(float* __restrict__ out0) {
    int gid = blockIdx.x * 256 + threadIdx.x;
    f32x4 z = {0.f, 0.f, 0.f, 0.f};
    ((f32x4*)out0)[gid] = z;
}

// ---------------- x f32 -> bf16 ----------------
__global__ void __launch_bounds__(256) xcvt_kernel(const float* __restrict__ x, u16* __restrict__ xb) {
    size_t gid = (size_t)blockIdx.x * 256 + threadIdx.x;
    const float4* s = (const float4*)x + gid * 2;
    float4 a = s[0], b = s[1];
    uint4 o;
    o.x = pkbf(a.x, a.y); o.y = pkbf(a.z, a.w);
    o.z = pkbf(b.x, b.y); o.w = pkbf(b.z, b.w);
    ((uint4*)xb)[gid] = o;
}

// ---------------- weight pack: src [e][K][N] f32 -> dst [e][N][K/2] u32 (bf16 k-pairs) ----------------
__global__ void __launch_bounds__(256)
pack_kernel(const float* __restrict__ src, u32* __restrict__ dst, int K, int N) {
    int e = blockIdx.z;
    int n0 = blockIdx.x * 64;
    int r0 = blockIdx.y * 128;          // k-row base (128 rows = 64 k2)
    __shared__ float sT[128][65];
    int tid = threadIdx.x;
    const float* sp = src + ((size_t)e * K + r0) * N + n0;
#pragma unroll
    for (int rep = 0; rep < 8; rep++) {
        int row = rep * 16 + (tid >> 4);
        int n4 = (tid & 15) * 4;
        float4 v = *(const float4*)(sp + (size_t)row * N + n4);
        sT[row][n4] = v.x; sT[row][n4 + 1] = v.y; sT[row][n4 + 2] = v.z; sT[row][n4 + 3] = v.w;
    }
    __syncthreads();
    int n = tid >> 2, q = tid & 3;
    u32* dp = dst + ((size_t)e * N + n0 + n) * (size_t)(K >> 1) + (r0 >> 1) + q * 16;
    uint4 o[4];
    u32* ow = (u32*)o;
#pragma unroll
    for (int j = 0; j < 16; j++) {
        int k2 = q * 16 + j;
        ow[j] = pkbf(sT[2 * k2][n], sT[2 * k2 + 1][n]);
    }
#pragma unroll
    for (int j = 0; j < 4; j++) ((uint4*)dp)[j] = o[j];
}

// ---------------- router (f32): logits + softmax top-2 + expert lists ----------------
__global__ void __launch_bounds__(256)
router_kernel(const float* __restrict__ x, const float* __restrict__ gw,
              float* __restrict__ logits_out, float* __restrict__ wbuf,
              int* __restrict__ cnt, int* __restrict__ idxlist) {
    int lane = threadIdx.x & 63;
    int t = blockIdx.x * 4 + (threadIdx.x >> 6);
    const float* xr = x + (size_t)t * H_DIM;
    float acc[NE];
#pragma unroll
    for (int e = 0; e < NE; e++) acc[e] = 0.f;
#pragma unroll
    for (int i = 0; i < 16; i++) {
        int hh = i * 64 + lane;
        float xv = xr[hh];
        const float4* grow = (const float4*)(gw + (size_t)hh * NE);
        float4 g0 = grow[0], g1 = grow[1];
        acc[0] += xv * g0.x; acc[1] += xv * g0.y;
        acc[2] += xv * g0.z; acc[3] += xv * g0.w;
        acc[4] += xv * g1.x; acc[5] += xv * g1.y;
        acc[6] += xv * g1.z; acc[7] += xv * g1.w;
    }
#pragma unroll
    for (int m = 32; m >= 1; m >>= 1) {
#pragma unroll
        for (int e = 0; e < NE; e++) acc[e] += __shfl_xor(acc[e], m, 64);
    }
    if (lane == 0) {
        float mx = acc[0];
#pragma unroll
        for (int e = 1; e < NE; e++) mx = fmaxf(mx, acc[e]);
        float p[NE];
#pragma unroll
        for (int e = 0; e < NE; e++) p[e] = __expf(acc[e] - mx);
        float4 l0, l1;
        l0.x = acc[0]; l0.y = acc[1]; l0.z = acc[2]; l0.w = acc[3];
        l1.x = acc[4]; l1.y = acc[5]; l1.z = acc[6]; l1.w = acc[7];
        float4* lrow_p = (float4*)(logits_out + (size_t)t * NE);
        lrow_p[0] = l0; lrow_p[1] = l1;
        int a = 0; float pa = p[0];
#pragma unroll
        for (int e = 1; e < NE; e++) if (p[e] > pa) { a = e; pa = p[e]; }
        int b = -1; float pb = -1.f;
#pragma unroll
        for (int e = 0; e < NE; e++) if (e != a && p[e] > pb) { b = e; pb = p[e]; }
        if (b < 0) { b = a ^ 1; pb = p[b]; }
        float inv = 1.f / (pa + pb);
        wbuf[2 * t]     = pa * inv;
        wbuf[2 * t + 1] = pb * inv;
        int pos = atomicAdd(&cnt[a], 1); idxlist[a * T_TOK + pos] = 2 * t;
        pos = atomicAdd(&cnt[b], 1);     idxlist[b * T_TOK + pos] = 2 * t + 1;
    }
}

// ---------------- grouped gate+up GEMM (I-chunk), two-pass double-buffered ----------------
// Tile 128x128, BK=64, 4 waves. 8-chunk 16B layout + XOR(&7) swizzle (R1's 0-conflict
// geometry). LDS = 2 x (A 16KB + B 16KB) = 64 KB -> 2 blocks/CU.
// Pass 0: K-sweep vs wg (accg); pass 1: K-sweep vs wu (accu). Each K-step:
// barrier -> stage NEXT step into other buffer (counted: loads fly across a full
// 32-MFMA compute phase) -> compute current. Pass boundary pipelined.
// Epilogue: silu fuse -> LDS tile -> coalesced 16B stores (no partial-line writes).
__global__ void __launch_bounds__(256, 2)
gateup_kernel(const u16* __restrict__ xb, const u32* __restrict__ wgp,
              const u32* __restrict__ wup, const int* __restrict__ cnt,
              const int* __restrict__ idxlist, u16* __restrict__ hchunk,
              int nbase, int nlen) {
    // XCD-grouped mapping: consecutive blocks on one XCD share the (e,n) B-strip.
    int NN = nlen >> 7;
    int pid = blockIdx.x;
    int xcd = pid & 7;
    int j = pid >> 3;
    int m = j & 63;
    int gs = j >> 6;
    int g = xcd + (gs << 3);
    int e = g / NN;
    int nb = g - e * NN;
    int c = cnt[e];
    int m0 = m * 128;
    if (m0 >= c) return;
    int n0l = nb * 128;
    int n0g = nbase + n0l;

    __shared__ alignas(16) u16 sA[2][128 * 64];   // 16 KB each
    __shared__ alignas(16) u32 sB[2][128 * 32];   // 16 KB each
    int tid = threadIdx.x;
    int wv = tid >> 6;

    int arow = tid >> 3;                 // 0..31
    int csw = tid & 7;                   // 16B chunk slot (8 per row)
    const u16* aP[4];
#pragma unroll
    for (int p = 0; p < 4; p++) {
        int jj = m0 + p * 32 + arow; if (jj > c - 1) jj = c - 1;
        int slot = idxlist[e * T_TOK + jj];
        aP[p] = xb + (size_t)(slot >> 1) * H_DIM + ((csw ^ (arow & 7)) << 3);
    }
    size_t bn = (size_t)e * I_DIM + n0g + arow;
    int bsw = (csw ^ (arow & 7)) << 2;   // u32 offset of source 16B chunk
    const u32* bgB = wgp + bn * 512 + bsw;
    const u32* buB = wup + bn * 512 + bsw;

    auto stage = [&](int k0, int buf, const u32* bB) {
#pragma unroll
        for (int p = 0; p < 4; p++)
            g2l16(aP[p] + k0, &sA[buf][(p * 256 + wv * 64) * 8]);
#pragma unroll
        for (int p = 0; p < 4; p++)
            g2l16(bB + (size_t)p * 32 * 512 + (k0 >> 1), &sB[buf][(p * 256 + wv * 64) * 4]);
    };

    int lane = tid & 63;
    int wm = (tid >> 7) & 1, wn = (tid >> 6) & 1;
    int lrow = lane & 15, quad = lane >> 4;
    f32x4 zero = {0.f, 0.f, 0.f, 0.f};
    f32x4 accg[4][4], accu[4][4];
#pragma unroll
    for (int mi = 0; mi < 4; mi++)
#pragma unroll
        for (int ni = 0; ni < 4; ni++) { accg[mi][ni] = zero; accu[mi][ni] = zero; }

    auto run_pass = [&](const u32* bBc, const u32* bBn, f32x4 (&acc)[4][4]) {
#pragma unroll 2
        for (int k0 = 0; k0 < H_DIM; k0 += 64) {
            int buf = (k0 >> 6) & 1;
            __syncthreads();             // drains prefetch issued one phase ago
            if (k0 + 64 < H_DIM) stage(k0 + 64, buf ^ 1, bBc);
            else if (bBn)        stage(0, buf ^ 1, bBn);   // pipeline pass boundary
#pragma unroll
            for (int kk = 0; kk < 2; kk++) {
                int cb = kk * 4 + quad;
                bf16x8 af[4]; F8 bf[4];
#pragma unroll
                for (int i = 0; i < 4; i++) {
                    int ra = wm * 64 + i * 16 + lrow;
                    af[i] = *(const bf16x8*)&sA[buf][(size_t)(ra * 8 + (cb ^ (ra & 7))) * 8];
                    int n = wn * 64 + i * 16 + lrow;
                    bf[i].v = *(const uint4*)&sB[buf][(size_t)(n * 8 + (cb ^ (n & 7))) * 4];
                }
#pragma unroll
                for (int mi = 0; mi < 4; mi++)
#pragma unroll
                    for (int ni = 0; ni < 4; ni++)
                        acc[mi][ni] = __builtin_amdgcn_mfma_f32_16x16x32_bf16(af[mi], bf[ni].f, acc[mi][ni], 0, 0, 0);
            }
        }
    };

    stage(0, 0, bgB);
    run_pass(bgB, buB, accg);
    run_pass(buB, nullptr, accu);

    // ---- epilogue: h = silu(g)*u via LDS tile, then coalesced 16B stores ----
    u16* hT = &sA[0][0];                 // 128x128 u16 = 32 KB (reuses both A buffers)
    __syncthreads();                     // all fragment reads complete before overwrite
#pragma unroll
    for (int mi = 0; mi < 4; mi++) {
#pragma unroll
        for (int r = 0; r < 4; r++) {
            int row = wm * 64 + mi * 16 + quad * 4 + r;
            int swz = (row & 7) << 3;
#pragma unroll
            for (int ni = 0; ni < 4; ni++) {
                int col = wn * 64 + ni * 16 + lrow;
                float gv = accg[mi][ni][r], uv = accu[mi][ni][r];
                float hv = gv * uv / (1.f + __expf(-gv));
                hT[row * 128 + (col ^ swz)] = f2bf(hv);
            }
        }
    }
    __syncthreads();
    {
        int row = tid & 127, half = tid >> 7;
        int grow = m0 + row;
        if (grow < c) {
            int slot = idxlist[e * T_TOK + grow];
            u16* dst = hchunk + (size_t)slot * nlen + n0l + half * 64;
            int swz = (row & 7) << 3;
#pragma unroll
            for (int j2 = 0; j2 < 8; j2++) {
                int colb = half * 64 + j2 * 8;
                *(uint4*)(dst + j2 * 8) = *(const uint4*)&hT[row * 128 + (colb ^ swz)];
            }
        }
    }
}

// ---------------- grouped down GEMM chunk (BK=64, double-buffered) ----------------
__global__ void __launch_bounds__(256, 2)
down_kernel(const u16* __restrict__ hchunk, const u32* __restrict__ wdp,
            const int* __restrict__ cnt, const int* __restrict__ idxlist,
            const float* __restrict__ wbuf, float* __restrict__ out0,
            float* __restrict__ ybuf, int kbase, int klen, int beta) {
    int pid = blockIdx.x;
    int xcd = pid & 7;
    int j = pid >> 3;
    int m = j & 63;
    int gs = j >> 6;
    int g = xcd + (gs << 3);   // 0..63 = e*8 + nb
    int e = g >> 3;
    int nb = g & 7;
    int c = cnt[e];
    int m0 = m * 128;
    if (m0 >= c) return;
    int n0 = nb * 128;

    __shared__ alignas(16) u16 sA[2][128 * 64];
    __shared__ alignas(16) u32 sB[2][128 * 32];
    int tid = threadIdx.x;
    int wv = tid >> 6;

    int arow = tid >> 3;
    int csw = tid & 7;
    const u16* aP[4];
#pragma unroll
    for (int p = 0; p < 4; p++) {
        int jj = m0 + p * 32 + arow; if (jj > c - 1) jj = c - 1;
        int slot = idxlist[e * T_TOK + jj];
        aP[p] = hchunk + (size_t)slot * klen + ((csw ^ (arow & 7)) << 3);
    }
    int bsw = (csw ^ (arow & 7)) << 2;
    const u32* bB = wdp + ((size_t)e * H_DIM + n0 + arow) * 1408 + (kbase >> 1) + bsw;

    auto stage = [&](int k0, int buf) {
#pragma unroll
        for (int p = 0; p < 4; p++)
            g2l16(aP[p] + k0, &sA[buf][(p * 256 + wv * 64) * 8]);
#pragma unroll
        for (int p = 0; p < 4; p++)
            g2l16(bB + (size_t)p * 32 * 1408 + (k0 >> 1), &sB[buf][(p * 256 + wv * 64) * 4]);
    };

    int lane = tid & 63;
    int wm = (tid >> 7) & 1, wn = (tid >> 6) & 1;
    int lrow = lane & 15, quad = lane >> 4;
    f32x4 zero = {0.f, 0.f, 0.f, 0.f};
    f32x4 acc[4][4];
#pragma unroll
    for (int mi = 0; mi < 4; mi++)
#pragma unroll
        for (int ni = 0; ni < 4; ni++) acc[mi][ni] = zero;

    stage(0, 0);
#pragma unroll 2
    for (int k0 = 0; k0 < klen; k0 += 64) {
        int buf = (k0 >> 6) & 1;
        __syncthreads();
        if (k0 + 64 < klen) stage(k0 + 64, buf ^ 1);
#pragma unroll
        for (int kk = 0; kk < 2; kk++) {
            int cb = kk * 4 + quad;
            bf16x8 af[4]; F8 bf[4];
#pragma unroll
            for (int i = 0; i < 4; i++) {
                int ra = wm * 64 + i * 16 + lrow;
                af[i] = *(const bf16x8*)&sA[buf][(size_t)(ra * 8 + (cb ^ (ra & 7))) * 8];
                int n = wn * 64 + i * 16 + lrow;
                bf[i].v = *(const uint4*)&sB[buf][(size_t)(n * 8 + (cb ^ (n & 7))) * 4];
            }
#pragma unroll
            for (int mi = 0; mi < 4; mi++)
#pragma unroll
                for (int ni = 0; ni < 4; ni++)
                    acc[mi][ni] = __builtin_amdgcn_mfma_f32_16x16x32_bf16(af[mi], bf[ni].f, acc[mi][ni], 0, 0, 0);
        }
    }
    // f32 stores: 16 lanes x 4B = full 64B line per instruction -> merges structurally
#pragma unroll
    for (int mi = 0; mi < 4; mi++) {
#pragma unroll
        for (int r = 0; r < 4; r++) {
            int grow = m0 + wm * 64 + mi * 16 + quad * 4 + r;
            if (grow < c) {
                int slot = idxlist[e * T_TOK + grow];
                if (ybuf) {
                    float* yrow = ybuf + (size_t)slot * H_DIM + n0 + wn * 64 + lrow;
                    if (beta) {
#pragma unroll
                        for (int ni = 0; ni < 4; ni++) yrow[ni * 16] += acc[mi][ni][r];
                    } else {
#pragma unroll
                        for (int ni = 0; ni < 4; ni++) yrow[ni * 16] = acc[mi][ni][r];
                    }
                } else {
                    float w = wbuf[slot];
                    float* yrow = out0 + (size_t)(slot >> 1) * H_DIM + n0 + wn * 64 + lrow;
#pragma unroll
                    for (int ni = 0; ni < 4; ni++)
                        atomicAdd(&yrow[ni * 16], w * acc[mi][ni][r]);
                }
            }
        }
    }
}

// ---------------- combine: out[t] = w0*y[2t] + w1*y[2t+1] ----------------
__global__ void __launch_bounds__(256)
combine_kernel(const float* __restrict__ ybuf, const float* __restrict__ wbuf,
               float* __restrict__ out0) {
    int gid = blockIdx.x * 256 + threadIdx.x;
    int t = gid >> 8;            // H_DIM/4 = 256 f32x4 per row
    int h4 = gid & 255;
    float w0 = wbuf[2 * t], w1 = wbuf[2 * t + 1];
    f32x4 a = ((const f32x4*)(ybuf + (size_t)(2 * t) * H_DIM))[h4];
    f32x4 b = ((const f32x4*)(ybuf + (size_t)(2 * t + 1) * H_DIM))[h4];
    f32x4 o;
#pragma unroll
    for (int i = 0; i < 4; i++) o[i] = w0 * a[i] + w1 * b[i];
    ((f32x4*)(out0 + (size_t)t * H_DIM))[h4] = o;
}

extern "C" void kernel_launch(void* const* d_in, const int* in_sizes, int n_in,
                              void* d_out, int out_size, void* d_ws, size_t ws_size,
                              hipStream_t stream) {
    (void)in_sizes; (void)n_in; (void)out_size;
    const float* x  = (const float*)d_in[0];
    const float* gw = (const float*)d_in[1];
    const float* wg = (const float*)d_in[2];
    const float* wu = (const float*)d_in[3];
    const float* wd = (const float*)d_in[4];
    float* out = (float*)d_out;
    float* logits = out + (size_t)T_TOK * H_DIM;
    char* ws = (char*)d_ws;

    size_t off = 0;
    auto take = [&](size_t sz) { char* p = ws + off; off += (sz + 255) & ~(size_t)255; return p; };
    int* cnt      = (int*)take(NE * 4);
    int* idxlist  = (int*)take((size_t)NE * T_TOK * 4);
    float* wbuf   = (float*)take((size_t)2 * T_TOK * 4);
    u16* xb       = (u16*)take((size_t)T_TOK * H_DIM * 2);            // 16.8 MB
    u32* wgp      = (u32*)take((size_t)NE * I_DIM * 512 * 4);         // 46.1 MB
    u32* wup      = (u32*)take((size_t)NE * I_DIM * 512 * 4);         // 46.1 MB
    u32* wdp      = (u32*)take((size_t)NE * H_DIM * 1408 * 4);        // 46.1 MB
    float* ybuf = nullptr;
    size_t ybytes = (size_t)2 * T_TOK * H_DIM * 4;                    // 67.1 MB
    size_t minh   = (size_t)2 * T_TOK * 128 * 2 + 256;
    if (ws_size >= off + ybytes + minh) ybuf = (float*)take(ybytes);
    int ich = I_DIM;
    while (ich > 128 && off + (size_t)2 * T_TOK * ich * 2 > ws_size) ich -= 128;
    u16* hchunk = (u16*)(ws + off);

    zero_cnt_kernel<<<1, 64, 0, stream>>>(cnt);
    if (!ybuf) zero_out_kernel<<<T_TOK * H_DIM / 4 / 256, 256, 0, stream>>>(out);
    pack_kernel<<<dim3(I_DIM / 64, H_DIM / 128, NE), 256, 0, stream>>>(wg, wgp, H_DIM, I_DIM);
    pack_kernel<<<dim3(I_DIM / 64, H_DIM / 128, NE), 256, 0, stream>>>(wu, wup, H_DIM, I_DIM);
    pack_kernel<<<dim3(H_DIM / 64, I_DIM / 128, NE), 256, 0, stream>>>(wd, wdp, I_DIM, H_DIM);
    xcvt_kernel<<<T_TOK * H_DIM / 8 / 256, 256, 0, stream>>>(x, xb);
    router_kernel<<<T_TOK / 4, 256, 0, stream>>>(x, gw, logits, wbuf, cnt, idxlist);
    for (int base = 0; base < I_DIM; base += ich) {
        int len = I_DIM - base; if (len > ich) len = ich;
        int NN = len / 128;
        gateup_kernel<<<64 * NN * NE, 256, 0, stream>>>(xb, wgp, wup, cnt, idxlist, hchunk, base, len);
        down_kernel<<<64 * 8 * NE, 256, 0, stream>>>(hchunk, wdp, cnt, idxlist, wbuf, out, ybuf, base, len, base > 0 ? 1 : 0);
    }
    if (ybuf) combine_kernel<<<T_TOK * H_DIM / 4 / 256, 256, 0, stream>>>(ybuf, wbuf, out);
}